// Round 13
// baseline (985.000 us; speedup 1.0000x reference)
//
#include <hip/hip_runtime.h>
#include <cstdint>
#include <cstddef>

namespace {

constexpr int Bb = 8;
constexpr int Nn = 2048;
constexpr int Dd = 1024;
constexpr int NT = 64;  // kv tiles of 32

typedef _Float16 half8 __attribute__((ext_vector_type(8)));
typedef float f32x4v __attribute__((ext_vector_type(4)));
typedef unsigned int v2u __attribute__((ext_vector_type(2)));
typedef unsigned int v4u __attribute__((ext_vector_type(4)));

__device__ __forceinline__ float fast_exp2(float x) {
  float r;
  asm("v_exp_f32 %0, %1\n\ts_nop 1" : "=v"(r) : "v"(x));
  return r;
}

// pack two f32 -> one u32 of 2x fp16 (RTZ); src0 -> low 16 bits
__device__ __forceinline__ unsigned cvt2(float a, float b) {
  return __builtin_bit_cast(unsigned, __builtin_amdgcn_cvt_pkrtz(a, b));
}

// quad-lane butterfly reductions via DPP quad_perm (VALU pipe).
__device__ __forceinline__ float quad_max(float v) {
  int a = __builtin_amdgcn_update_dpp(0, __builtin_bit_cast(int, v), 0xB1,
                                      0xF, 0xF, true);
  float m = fmaxf(v, __builtin_bit_cast(float, a));
  int b = __builtin_amdgcn_update_dpp(0, __builtin_bit_cast(int, m), 0x4E,
                                      0xF, 0xF, true);
  return fmaxf(m, __builtin_bit_cast(float, b));
}
__device__ __forceinline__ float quad_add(float v) {
  int a = __builtin_amdgcn_update_dpp(0, __builtin_bit_cast(int, v), 0xB1,
                                      0xF, 0xF, true);
  float s = v + __builtin_bit_cast(float, a);
  int b = __builtin_amdgcn_update_dpp(0, __builtin_bit_cast(int, s), 0x4E,
                                      0xF, 0xF, true);
  return s + __builtin_bit_cast(float, b);
}

__device__ __forceinline__ void barrier_lgkm() {
  asm volatile("s_waitcnt lgkmcnt(0)" ::: "memory");
  __builtin_amdgcn_s_barrier();
  __builtin_amdgcn_sched_barrier(0);
}
__device__ __forceinline__ void barrier_plain() {
  __builtin_amdgcn_s_barrier();
  __builtin_amdgcn_sched_barrier(0);
}

// fp32 -> packed fp16 stream (same element order, 2B/elem)
__global__ void convf16(const float* __restrict__ in, v4u* __restrict__ out) {
  const int n8 = Bb * Nn * Dd / 8;
  int i = blockIdx.x * blockDim.x + threadIdx.x;
  const int stride = gridDim.x * blockDim.x;
  const f32x4v* in4 = (const f32x4v*)in;
  for (; i < n8; i += stride) {
    f32x4v a = in4[2 * i], b = in4[2 * i + 1];
    v4u p;
    p[0] = cvt2(a[0], a[1]);
    p[1] = cvt2(a[2], a[3]);
    p[2] = cvt2(b[0], b[1]);
    p[3] = cvt2(b[2], b[3]);
    out[i] = p;
  }
}

template <int WS>
__device__ __forceinline__ v4u ld8h(const float* f32p, const v4u* h16p) {
  if constexpr (WS) {
    return *h16p;
  } else {
    f32x4v a = *(const f32x4v*)f32p;
    f32x4v b = *(const f32x4v*)(f32p + 4);
    v4u p;
    p[0] = cvt2(a[0], a[1]);
    p[1] = cvt2(a[2], a[3]);
    p[2] = cvt2(b[0], b[1]);
    p[3] = cvt2(b[2], b[3]);
    return p;
  }
}

// Flash attention fwd (no scale), K == V == Y. QB=16, KVB=32.
// 256 threads = 4 waves, wave w = d-slice (256 d). Two blocks co-resident
// per CU (LDS ~76KB, regs <=256 incl AGPR) -> independent barrier groups.
//  ph A: S(t) 16 MFMA | LOADY(s,t+1) | pscr2 wr                 [B1]
//  ph B: w0: softmax(t)+issue trA; w1-3: issue trA (subs 0-7)   [B2]
//  ph C: pa + rescale + MFMA 0-7 | issue trB + MFMA 8-15        [B3]
//  ph D: STAGE_WR(s -> ybuf)
template <int WS>
__global__ __launch_bounds__(256, 2) void flash_fwd(
    const float* __restrict__ Qf, const float* __restrict__ Yf,
    const v4u* __restrict__ Qw, const v4u* __restrict__ Yw,
    float* __restrict__ Om) {
  // ybuf tr-window layout:
  // addr(kv,d) = (kv>>2)*8192 + (d>>4)*128 + (kv&3)*32 + (d&15)*2
  __shared__ __attribute__((aligned(128))) char ybuf[65536];
  __shared__ __attribute__((aligned(16))) float pscr2[4][16][36];
  __shared__ __attribute__((aligned(16))) char Pb[1024];  // [oct][q] 16B
  __shared__ float sscale[16];
  __shared__ float sinvl[16];
  __shared__ int sflag[1];

  const int tid = (int)threadIdx.x;
  const int w = tid >> 6, l = tid & 63;
  const int lm = l & 15, g = (l >> 4) & 3;
  const int bid = (int)blockIdx.x, batch = bid & 7, row0 = (bid >> 3) * 16;
  const size_t bY = (size_t)batch * Nn;

  // ---- Q fragments (B-operand): lane(lm,g): q = lm,
  // d = w*256 + ks*32 + g*8 + i   (ks = 0..7)
  v4u qreg[8];
#pragma unroll
  for (int ks = 0; ks < 8; ++ks) {
    const int rr = row0 + lm;
    const int dd_ = w * 256 + ks * 32 + g * 8;
    qreg[ks] = ld8h<WS>(Qf + (size_t)(bY + rr) * Dd + dd_,
                        Qw + (size_t)(bY + rr) * 128 + (dd_ >> 3));
  }

  // s[h][ks] = Y[kv = h*16+lm][d = w*256+ks*32+g*8 ..+7] (S A-fragments)
  v4u s[2][8];
#define LOADY(t_)                                                             \
  do {                                                                        \
    _Pragma("unroll") for (int h = 0; h < 2; ++h)                             \
        _Pragma("unroll") for (int ks = 0; ks < 8; ++ks) {                    \
      const int rr_ = (t_)*32 + h * 16 + lm;                                  \
      const int dd_ = w * 256 + ks * 32 + g * 8;                              \
      s[h][ks] = ld8h<WS>(Yf + (size_t)(bY + rr_) * Dd + dd_,                 \
                          Yw + (size_t)(bY + rr_) * 128 + (dd_ >> 3));        \
    }                                                                         \
  } while (0)

  const unsigned sbase =
      (unsigned)((lm >> 2) * 8192 + (w * 16 + (g >> 1)) * 128 +
                 (lm & 3) * 32 + (g & 1) * 16);
#define STAGE_WR()                                                            \
  do {                                                                        \
    _Pragma("unroll") for (int h = 0; h < 2; ++h)                             \
        _Pragma("unroll") for (int ks = 0; ks < 8; ++ks)                      \
        *(v4u*)(ybuf + sbase + h * 32768u + ks * 256) = s[h][ks];             \
  } while (0)

  LOADY(0);
  STAGE_WR();

  f32x4v Oacc[16];
#pragma unroll
  for (int i = 0; i < 16; ++i)
#pragma unroll
    for (int j = 0; j < 4; ++j) Oacc[i][j] = 0.0f;

  float m_run = -__builtin_inff();
  float l_run = 0.0f;
  const unsigned ylds = (unsigned)(uintptr_t)&ybuf[0];
  constexpr float L2E = 1.44269504088896f;

  // issue 16 tr reads for d-subtiles [SB, SB+8): kv windows 2g, 2g+1
#define ISSUE_TR(dst, SB)                                                     \
  do {                                                                        \
    _Pragma("unroll") for (int sub = 0; sub < 8; ++sub) {                     \
      const unsigned a0 = ylds + (unsigned)((2 * g) * 8192 +                  \
                                            (w * 16 + (SB) + sub) * 128 +    \
                                            lm * 8);                          \
      asm volatile("ds_read_b64_tr_b16 %0, %1"                                \
                   : "=v"(dst[sub * 2])                                       \
                   : "v"(a0));                                                \
      asm volatile("ds_read_b64_tr_b16 %0, %1"                                \
                   : "=v"(dst[sub * 2 + 1])                                   \
                   : "v"(a0 + 8192u));                                        \
    }                                                                         \
  } while (0)

  __syncthreads();

  for (int t = 0; t < NT; ++t) {
    // ---- ph A: S MFMAs + prefetch + partial store
    f32x4v acc0 = {0.f, 0.f, 0.f, 0.f}, acc1 = {0.f, 0.f, 0.f, 0.f};
#pragma unroll
    for (int ks = 0; ks < 8; ++ks) {
      acc0 = __builtin_amdgcn_mfma_f32_16x16x32_f16(
          __builtin_bit_cast(half8, s[0][ks]), __builtin_bit_cast(half8, qreg[ks]),
          acc0, 0, 0, 0);
      acc1 = __builtin_amdgcn_mfma_f32_16x16x32_f16(
          __builtin_bit_cast(half8, s[1][ks]), __builtin_bit_cast(half8, qreg[ks]),
          acc1, 0, 0, 0);
    }
    LOADY((t + 1) & 63);
    // D[kv][q]: kv-row = g*4+r (+h*16), q-col = lm
    *(f32x4v*)&pscr2[w][lm][g * 4] = acc0;
    *(f32x4v*)&pscr2[w][lm][16 + g * 4] = acc1;
    barrier_lgkm();  // B1: partials + ybuf(t) visible

    // ---- ph B: softmax (wave 0) || tr issue (subs 0-7)
    v2u trrA[16];
    if (w == 0) {
      __builtin_amdgcn_s_setprio(1);
      const int rq = l >> 2;  // q row
      const int c = l & 3;    // kv octet
      f32x4v lo = {0.f, 0.f, 0.f, 0.f}, hi = {0.f, 0.f, 0.f, 0.f};
#pragma unroll
      for (int s_ = 0; s_ < 4; ++s_) {
        lo += *(const f32x4v*)&pscr2[s_][rq][c * 8];
        hi += *(const f32x4v*)&pscr2[s_][rq][c * 8 + 4];
      }
      float pm = fmaxf(fmaxf(fmaxf(lo[0], lo[1]), fmaxf(lo[2], lo[3])),
                       fmaxf(fmaxf(hi[0], hi[1]), fmaxf(hi[2], hi[3])));
      pm = quad_max(pm);
      bool defer = (pm <= m_run + 8.0f);
      bool allw = (bool)__all((int)defer);
      float scale = 1.0f;
      if (!allw) {
        float mn = fmaxf(m_run, pm);
        scale = fast_exp2((m_run - mn) * L2E);
        m_run = mn;
      }
      f32x4v ea, eb;
#pragma unroll
      for (int i = 0; i < 4; ++i) {
        ea[i] = fast_exp2((lo[i] - m_run) * L2E);
        eb[i] = fast_exp2((hi[i] - m_run) * L2E);
      }
      float ps = (ea[0] + ea[1]) + (ea[2] + ea[3]) + (eb[0] + eb[1]) +
                 (eb[2] + eb[3]);
      ps = quad_add(ps);
      l_run = l_run * scale + ps;
      v4u pk;
      pk[0] = cvt2(ea[0], ea[1]);
      pk[1] = cvt2(ea[2], ea[3]);
      pk[2] = cvt2(eb[0], eb[1]);
      pk[3] = cvt2(eb[2], eb[3]);
      *(v4u*)(Pb + c * 256 + rq * 16) = pk;  // P[q rq][kv c*8..+7]
      if (c == 0) sscale[rq] = scale;
      if (l == 0) sflag[0] = allw ? 0 : 1;
      __builtin_amdgcn_s_setprio(0);
      ISSUE_TR(trrA, 0);
    } else {
      ISSUE_TR(trrA, 0);
    }
    barrier_lgkm();  // B2: P + stats visible; trA data in regs

    // ---- ph C: PV
    half8 pa = *(const half8*)(Pb + g * 256 + lm * 16);  // P[q=lm][kv g*8..+7]
    if (sflag[0]) {
#pragma unroll
      for (int sub = 0; sub < 16; ++sub)
#pragma unroll
        for (int r = 0; r < 4; ++r) Oacc[sub][r] *= sscale[g * 4 + r];
    }
    asm volatile("s_waitcnt lgkmcnt(0)" ::: "memory");
    __builtin_amdgcn_sched_barrier(0);
#pragma unroll
    for (int sub = 0; sub < 8; ++sub) {
      v4u bu;
      bu[0] = trrA[sub * 2][0];
      bu[1] = trrA[sub * 2][1];
      bu[2] = trrA[sub * 2 + 1][0];
      bu[3] = trrA[sub * 2 + 1][1];
      Oacc[sub] = __builtin_amdgcn_mfma_f32_16x16x32_f16(
          pa, __builtin_bit_cast(half8, bu), Oacc[sub], 0, 0, 0);
    }
    v2u trrB[16];
    ISSUE_TR(trrB, 8);
    asm volatile("s_waitcnt lgkmcnt(0)" ::: "memory");
    __builtin_amdgcn_sched_barrier(0);
#pragma unroll
    for (int sub = 0; sub < 8; ++sub) {
      v4u bu;
      bu[0] = trrB[sub * 2][0];
      bu[1] = trrB[sub * 2][1];
      bu[2] = trrB[sub * 2 + 1][0];
      bu[3] = trrB[sub * 2 + 1][1];
      Oacc[8 + sub] = __builtin_amdgcn_mfma_f32_16x16x32_f16(
          pa, __builtin_bit_cast(half8, bu), Oacc[8 + sub], 0, 0, 0);
    }
    barrier_plain();  // B3: ybuf reads done, free for overwrite
    STAGE_WR();       // tile t+1 -> ybuf
  }

  // ---- epilogue: D[q = g*4+r][d = w*256 + sub*16 + lm]
  if (w == 0 && (l & 3) == 0) sinvl[l >> 2] = 1.0f / l_run;
  __syncthreads();
#pragma unroll
  for (int sub = 0; sub < 16; ++sub)
#pragma unroll
    for (int r = 0; r < 4; ++r) {
      const int q_ = g * 4 + r;
      Om[(size_t)(bY + row0 + q_) * Dd + w * 256 + sub * 16 + lm] =
          Oacc[sub][r] * sinvl[q_];
    }
#undef ISSUE_TR
#undef STAGE_WR
#undef LOADY
}

}  // namespace

extern "C" void kernel_launch(void* const* d_in, const int* in_sizes, int n_in,
                              void* d_out, int out_size, void* d_ws,
                              size_t ws_size, hipStream_t stream) {
  (void)in_sizes; (void)n_in; (void)out_size;
  const float* x = (const float*)d_in[0];
  const float* y = (const float*)d_in[1];
  float* A = (float*)d_out;
  float* Bo = A + (size_t)Bb * Nn * Dd;
  const size_t halfws = (size_t)Bb * Nn * Dd * 2;  // 32 MiB per matrix
  dim3 fg(Bb * (Nn / 16)), fb(256);
  if (d_ws != nullptr && ws_size >= 2 * halfws) {
    v4u* Xw = (v4u*)d_ws;
    v4u* Yw = (v4u*)((char*)d_ws + halfws);
    hipLaunchKernelGGL(convf16, dim3(2048), dim3(256), 0, stream, x, Xw);
    hipLaunchKernelGGL(convf16, dim3(2048), dim3(256), 0, stream, y, Yw);
    hipLaunchKernelGGL(flash_fwd<1>, fg, fb, 0, stream, x, y, Xw, Yw, A);
    hipLaunchKernelGGL(flash_fwd<1>, fg, fb, 0, stream, y, x, Yw, Xw, Bo);
  } else {
    hipLaunchKernelGGL(flash_fwd<0>, fg, fb, 0, stream, x, y, (const v4u*)x,
                       (const v4u*)y, A);
    hipLaunchKernelGGL(flash_fwd<0>, fg, fb, 0, stream, y, x, (const v4u*)y,
                       (const v4u*)x, Bo);
  }
}

// Round 14
// 549.852 us; speedup vs baseline: 1.7914x; 1.7914x over previous
//
#include <hip/hip_runtime.h>
#include <cstdint>
#include <cstddef>

namespace {

constexpr int Bb = 8;
constexpr int Nn = 2048;
constexpr int Dd = 1024;
constexpr int NT = 64;  // kv tiles of 32

typedef _Float16 half8 __attribute__((ext_vector_type(8)));
typedef float f32x4v __attribute__((ext_vector_type(4)));
typedef float f32x16v __attribute__((ext_vector_type(16)));
typedef unsigned int v2u __attribute__((ext_vector_type(2)));
typedef unsigned int v4u __attribute__((ext_vector_type(4)));

__device__ __forceinline__ float fast_exp2(float x) {
  float r;
  asm("v_exp_f32 %0, %1\n\ts_nop 1" : "=v"(r) : "v"(x));
  return r;
}

// pack two f32 -> one u32 of 2x fp16 (RTZ); src0 -> low 16 bits
__device__ __forceinline__ unsigned cvt2(float a, float b) {
  return __builtin_bit_cast(unsigned, __builtin_amdgcn_cvt_pkrtz(a, b));
}

// quad-lane butterfly reductions via DPP quad_perm (VALU pipe).
__device__ __forceinline__ float quad_max(float v) {
  int a = __builtin_amdgcn_update_dpp(0, __builtin_bit_cast(int, v), 0xB1,
                                      0xF, 0xF, true);
  float m = fmaxf(v, __builtin_bit_cast(float, a));
  int b = __builtin_amdgcn_update_dpp(0, __builtin_bit_cast(int, m), 0x4E,
                                      0xF, 0xF, true);
  return fmaxf(m, __builtin_bit_cast(float, b));
}
__device__ __forceinline__ float quad_add(float v) {
  int a = __builtin_amdgcn_update_dpp(0, __builtin_bit_cast(int, v), 0xB1,
                                      0xF, 0xF, true);
  float s = v + __builtin_bit_cast(float, a);
  int b = __builtin_amdgcn_update_dpp(0, __builtin_bit_cast(int, s), 0x4E,
                                      0xF, 0xF, true);
  return s + __builtin_bit_cast(float, b);
}

__device__ __forceinline__ void barrier_lgkm() {
  asm volatile("s_waitcnt lgkmcnt(0)" ::: "memory");
  __builtin_amdgcn_s_barrier();
  __builtin_amdgcn_sched_barrier(0);
}
__device__ __forceinline__ void barrier_plain() {
  __builtin_amdgcn_s_barrier();
  __builtin_amdgcn_sched_barrier(0);
}

// fp32 -> packed fp16 stream (same element order, 2B/elem)
__global__ void convf16(const float* __restrict__ in, v4u* __restrict__ out) {
  const int n8 = Bb * Nn * Dd / 8;
  int i = blockIdx.x * blockDim.x + threadIdx.x;
  const int stride = gridDim.x * blockDim.x;
  const f32x4v* in4 = (const f32x4v*)in;
  for (; i < n8; i += stride) {
    f32x4v a = in4[2 * i], b = in4[2 * i + 1];
    v4u p;
    p[0] = cvt2(a[0], a[1]);
    p[1] = cvt2(a[2], a[3]);
    p[2] = cvt2(b[0], b[1]);
    p[3] = cvt2(b[2], b[3]);
    out[i] = p;
  }
}

template <int WS>
__device__ __forceinline__ v4u ld8h(const float* f32p, const v4u* h16p) {
  if constexpr (WS) {
    return *h16p;
  } else {
    f32x4v a = *(const f32x4v*)f32p;
    f32x4v b = *(const f32x4v*)(f32p + 4);
    v4u p;
    p[0] = cvt2(a[0], a[1]);
    p[1] = cvt2(a[2], a[3]);
    p[2] = cvt2(b[0], b[1]);
    p[3] = cvt2(b[2], b[3]);
    return p;
  }
}

// Flash attention fwd (no scale), K == V == Y. 512 threads = 8 waves:
// wave = (kvf in 0..1) x (ds in 0..3, 256-d slice). QB=32, KVB=32.
// R11 schedule; pscr2 rows padded to 33 floats + q-rotated kv-quarters
// (conflict fix); B2 drains lgkm only for softmax waves.
template <int WS>
__global__ __launch_bounds__(512, 2) void flash_fwd(
    const float* __restrict__ Qf, const float* __restrict__ Yf,
    const v4u* __restrict__ Qw, const v4u* __restrict__ Yw,
    float* __restrict__ Om) {
  // ybuf tr-window layout:
  // addr(kv,d) = (kv>>2)*8192 + (d>>4)*128 + (kv&3)*32 + (d&15)*2
  __shared__ __attribute__((aligned(128))) char ybuf[65536];
  // pscr2[ds][q][8 quarters x 4 f32 + pad]; quarter rotated by (qt+q)&7
  __shared__ __attribute__((aligned(16))) float pscr2[4][32][33];
  __shared__ __attribute__((aligned(16))) char Pb[2048];  // [oct][q] 16B
  __shared__ float sscale[32];
  __shared__ float sinvl[32];
  __shared__ int sflag[2];

  const int tid = (int)threadIdx.x;
  const int w = tid >> 6, l = tid & 63;
  const int lm = l & 15, g = (l >> 4) & 3, g2 = (l >> 5) & 1, l31 = l & 31;
  const int kvf = w >> 2, ds = w & 3;
  const int bid = (int)blockIdx.x, batch = bid & 7, row0 = (bid >> 3) * 32;
  const size_t bY = (size_t)batch * Nn;

  // ---- Q fragments (B-operand): lane(lm,g): q = qh*16+lm,
  // d = ds*256 + ks*32 + g*8 + i   (ks = 0..7)
  v4u qreg[2][8];
#pragma unroll
  for (int qh = 0; qh < 2; ++qh)
#pragma unroll
    for (int ks = 0; ks < 8; ++ks) {
      const int rr = row0 + qh * 16 + lm;
      const int dd_ = ds * 256 + ks * 32 + g * 8;
      qreg[qh][ks] = ld8h<WS>(Qf + (size_t)(bY + rr) * Dd + dd_,
                              Qw + (size_t)(bY + rr) * 128 + (dd_ >> 3));
    }

#define LOADY(dst, t_)                                                        \
  do {                                                                        \
    const int rr_ = (t_)*32 + kvf * 16 + lm;                                  \
    _Pragma("unroll") for (int ks = 0; ks < 8; ++ks) {                        \
      const int dd_ = ds * 256 + ks * 32 + g * 8;                             \
      dst[ks] = ld8h<WS>(Yf + (size_t)(bY + rr_) * Dd + dd_,                  \
                         Yw + (size_t)(bY + rr_) * 128 + (dd_ >> 3));         \
    }                                                                         \
  } while (0)

  // staging write: lane(lm,g) kv=kvf*16+lm, d=ds*256+ks*32+g*8 (16B half-row)
  const unsigned sbase =
      (unsigned)((kvf * 4 + (lm >> 2)) * 8192 + (ds * 16 + (g >> 1)) * 128 +
                 (lm & 3) * 32 + (g & 1) * 16);
#define STAGE_WR(SRC)                                                         \
  do {                                                                        \
    _Pragma("unroll") for (int ks = 0; ks < 8; ++ks)                          \
        *(v4u*)(ybuf + sbase + ks * 256) = SRC[ks];                           \
  } while (0)

  v4u s[8];
  LOADY(s, 0);
  STAGE_WR(s);

  f32x16v Oacc[4];
#pragma unroll
  for (int i = 0; i < 4; ++i)
#pragma unroll
    for (int j = 0; j < 16; ++j) Oacc[i][j] = 0.0f;

  float m_run = -__builtin_inff();
  float l_run = 0.0f;
  const unsigned ylds = (unsigned)(uintptr_t)&ybuf[0];
  constexpr float L2E = 1.44269504088896f;

  v2u trr[16];

#define ISSUE_TR()                                                            \
  do {                                                                        \
    _Pragma("unroll") for (int kb = 0; kb < 2; ++kb)                          \
        _Pragma("unroll") for (int df = 0; df < 4; ++df) {                    \
      const unsigned wb =                                                     \
          ylds + (unsigned)((kb * 4 + g2 * 2) * 8192 +                        \
                            ((w * 4 + df) * 2 + (l31 >> 4)) * 128 +           \
                            (l31 & 15) * 8);                                  \
      asm volatile("ds_read_b64_tr_b16 %0, %1"                                \
                   : "=v"(trr[kb * 8 + df * 2])                               \
                   : "v"(wb));                                                \
      asm volatile("ds_read_b64_tr_b16 %0, %1"                                \
                   : "=v"(trr[kb * 8 + df * 2 + 1])                           \
                   : "v"(wb + 8192u));                                        \
    }                                                                         \
  } while (0)

  __syncthreads();

#define TILE_BODY(t_)                                                         \
  do {                                                                        \
    f32x4v acc0 = {0.f, 0.f, 0.f, 0.f}, acc1 = {0.f, 0.f, 0.f, 0.f};          \
    _Pragma("unroll") for (int ks = 0; ks < 8; ++ks) {                        \
      half8 av = __builtin_bit_cast(half8, s[ks]);                            \
      acc0 = __builtin_amdgcn_mfma_f32_16x16x32_f16(                          \
          av, __builtin_bit_cast(half8, qreg[0][ks]), acc0, 0, 0, 0);         \
      acc1 = __builtin_amdgcn_mfma_f32_16x16x32_f16(                          \
          av, __builtin_bit_cast(half8, qreg[1][ks]), acc1, 0, 0, 0);         \
    }                                                                         \
    LOADY(s, ((t_) + 1) & 63);                                                \
    /* rotated quarter stores: quarter qt = kvf*4+g, key = q&7 (= lm&7) */    \
    *(f32x4v*)&pscr2[ds][lm][((kvf * 4 + g + lm) & 7) * 4] = acc0;            \
    *(f32x4v*)&pscr2[ds][16 + lm][((kvf * 4 + g + lm) & 7) * 4] = acc1;       \
    barrier_lgkm(); /* B1: partials + ybuf(t) visible */                      \
    if (w >= 2) {                                                             \
      ISSUE_TR();                                                             \
    } else {                                                                  \
      __builtin_amdgcn_s_setprio(1);                                          \
      const int rq = w * 16 + (l >> 2); /* global q row */                    \
      const int c = l & 3;              /* kv octet */                        \
      f32x4v lo = {0.f, 0.f, 0.f, 0.f}, hi = {0.f, 0.f, 0.f, 0.f};            \
      _Pragma("unroll") for (int s_ = 0; s_ < 4; ++s_) {                      \
        lo += *(const f32x4v*)&pscr2[s_][rq][((2 * c + rq) & 7) * 4];         \
        hi += *(const f32x4v*)&pscr2[s_][rq][((2 * c + 1 + rq) & 7) * 4];     \
      }                                                                       \
      float pm = fmaxf(fmaxf(fmaxf(lo[0], lo[1]), fmaxf(lo[2], lo[3])),       \
                       fmaxf(fmaxf(hi[0], hi[1]), fmaxf(hi[2], hi[3])));      \
      pm = quad_max(pm);                                                      \
      bool defer = (pm <= m_run + 8.0f);                                      \
      bool allw = (bool)__all((int)defer);                                    \
      float scale = 1.0f;                                                     \
      if (!allw) {                                                            \
        float mn = fmaxf(m_run, pm);                                          \
        scale = fast_exp2((m_run - mn) * L2E);                                \
        m_run = mn;                                                           \
      }                                                                       \
      f32x4v ea, eb;                                                          \
      _Pragma("unroll") for (int i = 0; i < 4; ++i) {                         \
        ea[i] = fast_exp2((lo[i] - m_run) * L2E);                             \
        eb[i] = fast_exp2((hi[i] - m_run) * L2E);                             \
      }                                                                       \
      float ps = (ea[0] + ea[1]) + (ea[2] + ea[3]) + (eb[0] + eb[1]) +        \
                 (eb[2] + eb[3]);                                             \
      ps = quad_add(ps);                                                      \
      l_run = l_run * scale + ps;                                             \
      v4u pk;                                                                 \
      pk[0] = cvt2(ea[0], ea[1]);                                             \
      pk[1] = cvt2(ea[2], ea[3]);                                             \
      pk[2] = cvt2(eb[0], eb[1]);                                             \
      pk[3] = cvt2(eb[2], eb[3]);                                             \
      *(v4u*)(Pb + c * 512 + rq * 16) = pk;                                   \
      if (c == 0) sscale[rq] = scale;                                         \
      if (l == 0) sflag[w] = allw ? 0 : 1;                                    \
      __builtin_amdgcn_s_setprio(0);                                          \
      /* drain OUR P/stat writes before the barrier, then issue tr */         \
      asm volatile("s_waitcnt lgkmcnt(0)" ::: "memory");                      \
      ISSUE_TR();                                                             \
    }                                                                         \
    barrier_plain(); /* B2: P + stats visible (writers drained) */            \
    half8 pa0 = *(const half8*)(Pb + g2 * 512 + l31 * 16);                    \
    half8 pa1 = *(const half8*)(Pb + (2 + g2) * 512 + l31 * 16);              \
    if (sflag[0] | sflag[1]) {                                                \
      _Pragma("unroll") for (int df = 0; df < 4; ++df)                        \
          _Pragma("unroll") for (int r = 0; r < 16; ++r) {                    \
        const int q_ = (r & 3) + 8 * (r >> 2) + 4 * g2;                       \
        Oacc[df][r] *= sscale[q_];                                            \
      }                                                                       \
    }                                                                         \
    asm volatile("s_waitcnt lgkmcnt(0)" ::: "memory");                        \
    __builtin_amdgcn_sched_barrier(0);                                        \
    _Pragma("unroll") for (int kb = 0; kb < 2; ++kb)                          \
        _Pragma("unroll") for (int df = 0; df < 4; ++df) {                    \
      v4u bu;                                                                 \
      bu[0] = trr[kb * 8 + df * 2][0];                                        \
      bu[1] = trr[kb * 8 + df * 2][1];                                        \
      bu[2] = trr[kb * 8 + df * 2 + 1][0];                                    \
      bu[3] = trr[kb * 8 + df * 2 + 1][1];                                    \
      Oacc[df] = __builtin_amdgcn_mfma_f32_32x32x16_f16(                      \
          kb ? pa1 : pa0, __builtin_bit_cast(half8, bu), Oacc[df], 0, 0, 0);  \
    }                                                                         \
    barrier_plain(); /* B3: PV/pscr/Pb reads done, ybuf free */               \
    STAGE_WR(s);                                                              \
  } while (0)

  for (int t = 0; t < NT; ++t) {
    TILE_BODY(t);
  }

  // ---- epilogue
  if (w < 2 && (l & 3) == 0) sinvl[w * 16 + (l >> 2)] = 1.0f / l_run;
  __syncthreads();
#pragma unroll
  for (int df = 0; df < 4; ++df)
#pragma unroll
    for (int r = 0; r < 16; ++r) {
      const int q_ = (r & 3) + 8 * (r >> 2) + 4 * g2;
      const float inv = sinvl[q_];
      Om[(size_t)(bY + row0 + q_) * Dd + (w * 4 + df) * 32 + l31] =
          Oacc[df][r] * inv;
    }
#undef TILE_BODY
#undef ISSUE_TR
#undef STAGE_WR
#undef LOADY
}

}  // namespace

extern "C" void kernel_launch(void* const* d_in, const int* in_sizes, int n_in,
                              void* d_out, int out_size, void* d_ws,
                              size_t ws_size, hipStream_t stream) {
  (void)in_sizes; (void)n_in; (void)out_size;
  const float* x = (const float*)d_in[0];
  const float* y = (const float*)d_in[1];
  float* A = (float*)d_out;
  float* Bo = A + (size_t)Bb * Nn * Dd;
  const size_t halfws = (size_t)Bb * Nn * Dd * 2;  // 32 MiB per matrix
  dim3 fg(512), fb(512);
  if (d_ws != nullptr && ws_size >= 2 * halfws) {
    v4u* Xw = (v4u*)d_ws;
    v4u* Yw = (v4u*)((char*)d_ws + halfws);
    hipLaunchKernelGGL(convf16, dim3(2048), dim3(256), 0, stream, x, Xw);
    hipLaunchKernelGGL(convf16, dim3(2048), dim3(256), 0, stream, y, Yw);
    hipLaunchKernelGGL(flash_fwd<1>, fg, fb, 0, stream, x, y, Xw, Yw, A);
    hipLaunchKernelGGL(flash_fwd<1>, fg, fb, 0, stream, y, x, Yw, Xw, Bo);
  } else {
    hipLaunchKernelGGL(flash_fwd<0>, fg, fb, 0, stream, x, y, (const v4u*)x,
                       (const v4u*)y, A);
    hipLaunchKernelGGL(flash_fwd<0>, fg, fb, 0, stream, y, x, (const v4u*)y,
                       (const v4u*)x, Bo);
  }
}